// Round 1
// 340.597 us; speedup vs baseline: 1.0211x; 1.0211x over previous
//
#include <hip/hip_runtime.h>

#define FEAT 256
#define HID 128
#define NKEYS 2

typedef __bf16 bf16x8 __attribute__((ext_vector_type(8)));
typedef float f32x16 __attribute__((ext_vector_type(16)));

union Frag {
    bf16x8 v;
    unsigned u[4];
    uint4 q;
};

// pack two f32 -> two bf16 (round-half-up) in one v_perm
__device__ __forceinline__ unsigned pack_bf16_2(float f0, float f1) {
    unsigned u0 = __float_as_uint(f0) + 0x8000u;
    unsigned u1 = __float_as_uint(f1) + 0x8000u;
    return __builtin_amdgcn_perm(u1, u0, 0x07060302u);
}

// shifted softplus: softplus(x) - ln2
__device__ __forceinline__ float ssp(float x) {
    float sp = __logf(1.0f + __expf(x));
    sp = (x > 15.0f) ? x : sp;
    return sp - 0.69314718056f;
}

// largest m with off[m] <= g  (off[0]=0, off sorted, n_mols+1 entries)
__device__ __forceinline__ int find_mol(const int* __restrict__ off, int n_mols, int g) {
    int lo = 0, hi = n_mols;
    while (hi - lo > 1) {
        int mid = (lo + hi) >> 1;
        if (off[mid] <= g) lo = mid; else hi = mid;
    }
    return lo;
}

// Block 0: prefix-scan num_atoms (int32, falling back to int64 if the int32
// interpretation doesn't sum to n_atoms) + zero d_out. Scans are parallel
// (tree reduce + Hillis-Steele) -- no serial thread-0 loops.
// Blocks 1..256: pack W1 -> Bp bf16, layout Bp[c][k] (c = key*HID + j).
__global__ void prep_kernel(const void* __restrict__ num_atoms_raw,
                            const float* __restrict__ W1,
                            int n_mols, int n_atoms,
                            int* __restrict__ off,
                            unsigned short* __restrict__ Bp,
                            float* __restrict__ out, int out_n) {
    if (blockIdx.x > 0) {
        int idx = (blockIdx.x - 1) * 256 + threadIdx.x;   // 0..65535
        int c = idx >> 8;
        int k = idx & 255;
        int key = c >> 7, j = c & 127;
        float f = W1[(size_t)key * FEAT * HID + (size_t)k * HID + j];
        unsigned u = __float_as_uint(f);
        unsigned r = (u + 0x7FFFu + ((u >> 16) & 1u)) >> 16;   // RNE to bf16
        Bp[(size_t)c * FEAT + k] = (unsigned short)r;
        return;
    }
    // zero the output (atomically accumulated by gemm_fused)
    for (int i = threadIdx.x; i < out_n; i += 256) out[i] = 0.0f;

    __shared__ long long tsum[256];
    __shared__ int csum[256];
    int tid = threadIdx.x;
    const int* a32 = (const int*)num_atoms_raw;
    const long long* a64 = (const long long*)num_atoms_raw;
    int chunk = (n_mols + 255) >> 8;
    int lo = tid * chunk;
    if (lo > n_mols) lo = n_mols;
    int hi = lo + chunk;
    if (hi > n_mols) hi = n_mols;

    long long s32 = 0;
    for (int i = lo; i < hi; ++i) s32 += (long long)a32[i];
    tsum[tid] = s32;
    __syncthreads();
    // parallel tree reduce -> tsum[0] = total under int32 interpretation
    #pragma unroll
    for (int d = 128; d > 0; d >>= 1) {
        if (tid < d) tsum[tid] += tsum[tid + d];
        __syncthreads();
    }
    int mode = (tsum[0] == (long long)n_atoms) ? 0 : 1;
    long long s = s32;
    if (mode) {                      // only touch int64 view if int32 failed
        s = 0;
        for (int i = lo; i < hi; ++i) s += a64[i];
    }
    int v = (int)s;
    csum[tid] = v;
    __syncthreads();
    // Hillis-Steele inclusive scan over the 256 per-thread sums
    #pragma unroll
    for (int d = 1; d < 256; d <<= 1) {
        int t = (tid >= d) ? csum[tid - d] : 0;
        __syncthreads();
        csum[tid] += t;
        __syncthreads();
    }
    int run = csum[tid] - v;         // exclusive prefix
    for (int i = lo; i < hi; ++i) {
        off[i] = run;
        run += mode ? (int)a64[i] : a32[i];
    }
    if (hi >= n_mols) off[n_mols] = run;
}

// Fused: C = s_i @ B (bf16 MFMA, fp32 acc), +b1, shifted-softplus, .W2, +b2,
// segment-sum into out[key][mol] via atomics.
// Block: 256 threads = 4 waves; tile 64 rows x 256 cols; wave = 64x64.
// Double-buffered XOR-swizzled bf16 LDS A tile; chunk c+1 loads issued before
// chunk c's MFMAs so the pack->ds_write never sees raw HBM latency.
// launch_bounds(256,4): force total (VGPR+AGPR) <= 128 -> 4 waves/SIMD
// (previous build: 68 VGPR + 64 AGPR = 132 -> 3 waves/SIMD = the measured 29%).
__global__ __launch_bounds__(256, 4)
void gemm_fused(const float* __restrict__ A,
                const unsigned short* __restrict__ Bp,
                const float* __restrict__ b1,
                const float* __restrict__ W2,
                const float* __restrict__ b2,
                const int* __restrict__ off,
                float* __restrict__ out,
                int n_atoms, int n_mols) {
    // A chunk tile: 64 rows x 64 k (bf16) = 8 KB per buffer, as 16B units.
    // unit (row, u) stored at ldsA[b][row*8 + (u ^ (row&7))] -> conflict-free
    __shared__ uint4 ldsA[2][64 * 8];
    __shared__ float part[4][64];        // [wn][row]
    __shared__ float molacc[NKEYS][4];
    __shared__ int rowmol[64];           // mol index per tile row (precomputed)

    const int tid  = threadIdx.x;
    const int lane = tid & 63;
    const int wn   = tid >> 6;           // 0..3: 64-col group
    const int l31  = lane & 31;
    const int half = lane >> 5;          // 0/1
    const int m0   = blockIdx.x * 64;

    // ---- staging role: thread t covers row t/4, 16 floats at seg (t&3)
    const int srow = tid >> 2;
    const int sseg = tid & 3;
    int grow = m0 + srow;
    if (grow > n_atoms - 1) grow = n_atoms - 1;
    const float4* gsrc = (const float4*)(A + (size_t)grow * FEAT + sseg * 16);
    const int wu0 = srow * 8 + (((sseg * 2)    ) ^ (srow & 7));
    const int wu1 = srow * 8 + (((sseg * 2) + 1) ^ (srow & 7));

    // ---- compute role
    const int c0 = wn * 64 + l31;
    const unsigned short* bb0 = Bp + (size_t)c0 * FEAT + half * 8;
    const unsigned short* bb1 = Bp + (size_t)(c0 + 32) * FEAT + half * 8;
    const int rbase0 = l31 * 8;            // row l31
    const int rbase1 = (l31 + 32) * 8;     // row l31+32 (same &7 swizzle)
    const int rxor = l31 & 7;

    // issue chunk-0 global loads first; everything below overlaps them
    float4 f0 = gsrc[0];
    float4 f1 = gsrc[1];
    float4 f2 = gsrc[2];
    float4 f3 = gsrc[3];

    // hoisted epilogue prep: mol binary searches + scalar params
    if (tid < 64) {
        int gm = m0 + tid;
        if (gm > n_atoms - 1) gm = n_atoms - 1;
        rowmol[tid] = find_mol(off, n_mols, gm);
    }
    if (tid < NKEYS * 4) molacc[tid >> 2][tid & 3] = 0.0f;
    const float b1c0 = b1[c0], b1c1 = b1[c0 + 32];
    const float w2c0 = W2[c0], w2c1 = W2[c0 + 32];

    f32x16 acc00 = 0.0f, acc01 = 0.0f, acc10 = 0.0f, acc11 = 0.0f;

    // prologue: pack + write buffer 0
    {
        uint4 p0, p1;
        p0.x = pack_bf16_2(f0.x, f0.y);
        p0.y = pack_bf16_2(f0.z, f0.w);
        p0.z = pack_bf16_2(f1.x, f1.y);
        p0.w = pack_bf16_2(f1.z, f1.w);
        p1.x = pack_bf16_2(f2.x, f2.y);
        p1.y = pack_bf16_2(f2.z, f2.w);
        p1.z = pack_bf16_2(f3.x, f3.y);
        p1.w = pack_bf16_2(f3.z, f3.w);
        ldsA[0][wu0] = p0;
        ldsA[0][wu1] = p1;
    }
    __syncthreads();

    #pragma unroll
    for (int c = 0; c < FEAT / 64; ++c) {
        const int kb = c * 64;
        // issue next chunk's global loads NOW; consumed after this chunk's MFMAs
        if (c < 3) {
            f0 = gsrc[(c + 1) * 16 + 0];
            f1 = gsrc[(c + 1) * 16 + 1];
            f2 = gsrc[(c + 1) * 16 + 2];
            f3 = gsrc[(c + 1) * 16 + 3];
        }
        const uint4* lbuf = ldsA[c & 1];
        // rolling B-fragment prefetch: only 2 pairs live (16 VGPRs, not 32)
        Frag b0c, b1c, b0n, b1n;
        b0c.q = *(const uint4*)(bb0 + kb);
        b1c.q = *(const uint4*)(bb1 + kb);
        #pragma unroll
        for (int j = 0; j < 4; ++j) {
            if (j < 3) {
                b0n.q = *(const uint4*)(bb0 + kb + (j + 1) * 16);
                b1n.q = *(const uint4*)(bb1 + kb + (j + 1) * 16);
            }
            const int sw = (j * 2 + half) ^ rxor;
            Frag a0, a1;
            a0.q = lbuf[rbase0 + sw];
            a1.q = lbuf[rbase1 + sw];
            acc00 = __builtin_amdgcn_mfma_f32_32x32x16_bf16(a0.v, b0c.v, acc00, 0, 0, 0);
            acc01 = __builtin_amdgcn_mfma_f32_32x32x16_bf16(a0.v, b1c.v, acc01, 0, 0, 0);
            acc10 = __builtin_amdgcn_mfma_f32_32x32x16_bf16(a1.v, b0c.v, acc10, 0, 0, 0);
            acc11 = __builtin_amdgcn_mfma_f32_32x32x16_bf16(a1.v, b1c.v, acc11, 0, 0, 0);
            b0c = b0n;
            b1c = b1n;
        }
        // pack + write the *other* buffer (loads have had B-loads+16 MFMAs to land)
        if (c < 3) {
            uint4 p0, p1;
            p0.x = pack_bf16_2(f0.x, f0.y);
            p0.y = pack_bf16_2(f0.z, f0.w);
            p0.z = pack_bf16_2(f1.x, f1.y);
            p0.w = pack_bf16_2(f1.z, f1.w);
            p1.x = pack_bf16_2(f2.x, f2.y);
            p1.y = pack_bf16_2(f2.z, f2.w);
            p1.z = pack_bf16_2(f3.x, f3.y);
            p1.w = pack_bf16_2(f3.z, f3.w);
            ldsA[(c + 1) & 1][wu0] = p0;
            ldsA[(c + 1) & 1][wu1] = p1;
            __syncthreads();
        }
        // c == 3: no write, no barrier -- fall straight into the epilogue
    }

    // epilogue: act + .W2, column-reduce per row, stash in LDS
    #pragma unroll
    for (int rt = 0; rt < 2; ++rt) {
        const f32x16& Ac0 = rt ? acc10 : acc00;
        const f32x16& Ac1 = rt ? acc11 : acc01;
        #pragma unroll
        for (int r = 0; r < 16; ++r) {
            float t = ssp(Ac0[r] + b1c0) * w2c0 + ssp(Ac1[r] + b1c1) * w2c1;
            t += __shfl_xor(t, 1);
            t += __shfl_xor(t, 2);
            t += __shfl_xor(t, 4);
            t += __shfl_xor(t, 8);
            t += __shfl_xor(t, 16);
            if (l31 == r) {
                int row = rt * 32 + (r & 3) + 8 * (r >> 2) + 4 * half;
                part[wn][row] = t;
            }
        }
    }
    __syncthreads();

    if (tid < NKEYS * 64) {
        int key = tid >> 6, r = tid & 63;
        int gm = m0 + r;
        if (gm < n_atoms) {
            float val = part[2 * key][r] + part[2 * key + 1][r] + b2[key];
            int mol = rowmol[r];
            int ml  = mol - rowmol[0];
            if (ml < 4) atomicAdd(&molacc[key][ml], val);
            else        atomicAdd(&out[(size_t)key * n_mols + mol], val);
        }
    }
    __syncthreads();

    if (tid < NKEYS * 4) {
        int key = tid >> 2, ml = tid & 3;
        int mol = rowmol[0] + ml;
        if (mol < n_mols) {
            float v = molacc[key][ml];
            if (v != 0.0f) atomicAdd(&out[(size_t)key * n_mols + mol], v);
        }
    }
}

extern "C" void kernel_launch(void* const* d_in, const int* in_sizes, int n_in,
                              void* d_out, int out_size, void* d_ws, size_t ws_size,
                              hipStream_t stream) {
    const float* s_i      = (const float*)d_in[0];
    // d_in[1] = xyz: unused by the reference output
    const void*  num_atoms = d_in[2];
    const float* W1 = (const float*)d_in[3];
    const float* b1 = (const float*)d_in[4];
    const float* W2 = (const float*)d_in[5];
    const float* b2 = (const float*)d_in[6];
    int n_atoms = in_sizes[0] / FEAT;
    int n_mols  = in_sizes[2];
    float* out = (float*)d_out;

    int* off = (int*)d_ws;
    size_t off_bytes = (((size_t)(n_mols + 1) * 4) + 255) & ~(size_t)255;
    unsigned short* Bp = (unsigned short*)((char*)d_ws + off_bytes);

    int pack_blocks = (NKEYS * HID * FEAT) / 256;   // 256
    prep_kernel<<<1 + pack_blocks, 256, 0, stream>>>(num_atoms, W1, n_mols, n_atoms,
                                                     off, Bp, out, out_size);

    int gblocks = (n_atoms + 63) / 64;
    gemm_fused<<<gblocks, 256, 0, stream>>>(s_i, Bp, b1, W2, b2, off, out, n_atoms, n_mols);
}